// Round 13
// baseline (2742.901 us; speedup 1.0000x reference)
//
#include <hip/hip_runtime.h>

// ErbStage: conv0+LN+ReLU -> conv1+LN+ReLU -> spectral attention -> GRU(T=1000)
//           -> GRU(B=32 scan) + lsnr -> LN/conv2/LN/sigmoid mask.
//
// R13: GRU byte/load halving changed nothing (R9 1.43us/step f32 == R12
//      1.47us/step f16) -> NOT bandwidth-bound. 62% VALU busy on the 32
//      active CUs at 2 waves/SIMD -> issue/latency-bound. This round: 1024
//      threads (4 waves/SIMD), 4-way k-split, same SSA-sunk packed-f16
//      streaming (12 uint4 + 96 fdot2/thread/step).

typedef unsigned short u16;
typedef u16 u16x8 __attribute__((ext_vector_type(8)));
typedef short s16x8 __attribute__((ext_vector_type(8)));
typedef float f32x4 __attribute__((ext_vector_type(4)));
typedef _Float16 h2t __attribute__((ext_vector_type(2)));
typedef unsigned int u32x16 __attribute__((ext_vector_type(16)));

__device__ __forceinline__ float sigf(float x) { return 1.f / (1.f + __expf(-x)); }
__device__ __forceinline__ float tanhfast(float x) { return 2.f / (1.f + __expf(-2.f * x)) - 1.f; }
__device__ __forceinline__ float bf2f(u16 s) { union { unsigned u; float f; } x; x.u = ((unsigned)s) << 16; return x.f; }
__device__ __forceinline__ u16 f2bf(float f) {
  union { float f; unsigned u; } x; x.f = f;
  unsigned r = x.u + 0x7fffu + ((x.u >> 16) & 1u);
  return (u16)(r >> 16);
}
__device__ __forceinline__ h2t pk(float a, float b) {
  auto v = __builtin_amdgcn_cvt_pkrtz(a, b);
  union { decltype(v) i; h2t o; } u; u.i = v; return u.o;
}
__device__ __forceinline__ h2t bch(unsigned x) { return __builtin_bit_cast(h2t, x); }

// ---------------------------------------------------------------------------
// K0a: one-time W f32 -> bf16 convert (for MFMA GEMM)
// ---------------------------------------------------------------------------
__global__ __launch_bounds__(256) void k_wcvt(const float* __restrict__ W,
                                              u16* __restrict__ Wb)
{
  const size_t i = ((size_t)blockIdx.x * 256 + threadIdx.x) * 8;
  float4 a = *(const float4*)(W + i);
  float4 b = *(const float4*)(W + i + 4);
  u16x8 o;
  o[0] = f2bf(a.x); o[1] = f2bf(a.y); o[2] = f2bf(a.z); o[3] = f2bf(a.w);
  o[4] = f2bf(b.x); o[5] = f2bf(b.y); o[6] = f2bf(b.z); o[7] = f2bf(b.w);
  *(u16x8*)(Wb + i) = o;
}

// ---------------------------------------------------------------------------
// K0b: one-time whh f32 -> packed f16 pairs
// ---------------------------------------------------------------------------
__global__ __launch_bounds__(256) void k_wcvt2(const float* __restrict__ W,
                                               unsigned* __restrict__ Wp)
{
  const size_t i = (size_t)blockIdx.x * 256 + threadIdx.x;   // 98304 u32
  float2 a = *(const float2*)(W + i * 2);
  Wp[i] = __builtin_bit_cast(unsigned, pk(a.x, a.y));
}

// ---------------------------------------------------------------------------
// K1: fused frontend per (b,t)
// ---------------------------------------------------------------------------
__global__ __launch_bounds__(256) void k_frontend(
    const float* __restrict__ in,
    const float* __restrict__ w0c, const float* __restrict__ b0c,
    const float* __restrict__ g0, const float* __restrict__ be0,
    const float* __restrict__ w1c, const float* __restrict__ b1c,
    const float* __restrict__ g1, const float* __restrict__ be1,
    const float* __restrict__ qw, const float* __restrict__ qb,
    const float* __restrict__ kw, const float* __restrict__ kb,
    const float* __restrict__ vw, const float* __restrict__ vb,
    int bt0, u16* __restrict__ x1g, u16* __restrict__ gi)
{
  const int bt = bt0 + blockIdx.x, tid = threadIdx.x;
  __shared__ float s_in[34];
  __shared__ float s_x0[16][34];
  __shared__ float s_x1[8][34];
  __shared__ float s_q[64][36];
  __shared__ float s_k[64][36];
  __shared__ float s_v[32][68];
  __shared__ float s_sc[32][36];
  __shared__ float s_red[8];
  __shared__ float s_mu[16], s_rs[16];

  if (tid < 32) s_in[1 + tid] = in[(size_t)bt * 32 + tid];
  if (tid == 0) { s_in[0] = 0.f; s_in[33] = 0.f; }
  __syncthreads();

  // conv0 (1->16)
  #pragma unroll
  for (int i = 0; i < 2; ++i) {
    int o = tid + i * 256, c = o >> 5, f = o & 31;
    float a = b0c[c] + w0c[c*3]*s_in[f] + w0c[c*3+1]*s_in[f+1] + w0c[c*3+2]*s_in[f+2];
    s_x0[c][1 + f] = a;
  }
  __syncthreads();
  {
    int c = tid >> 4, i = tid & 15;
    float a = s_x0[c][1 + i], b = s_x0[c][17 + i];
    float s = a + b, ss = a * a + b * b;
    #pragma unroll
    for (int m = 8; m >= 1; m >>= 1) { s += __shfl_xor(s, m); ss += __shfl_xor(ss, m); }
    if (i == 0) { float mu = s * (1.f/32.f); s_mu[c] = mu; s_rs[c] = rsqrtf(ss * (1.f/32.f) - mu*mu + 1e-5f); }
  }
  __syncthreads();
  #pragma unroll
  for (int i = 0; i < 2; ++i) {
    int o = tid + i * 256, c = o >> 5, f = o & 31;
    float v = (s_x0[c][1 + f] - s_mu[c]) * s_rs[c] * g0[f] + be0[f];
    s_x0[c][1 + f] = fmaxf(v, 0.f);
  }
  if (tid < 16) { s_x0[tid][0] = 0.f; s_x0[tid][33] = 0.f; }
  __syncthreads();

  // conv1 (16->8) + ln1 + relu
  {
    int c = tid >> 5, f = tid & 31;
    float a = b1c[c];
    #pragma unroll
    for (int cc = 0; cc < 16; ++cc) {
      const float* wr = w1c + (c * 16 + cc) * 3;
      a += wr[0]*s_x0[cc][f] + wr[1]*s_x0[cc][f+1] + wr[2]*s_x0[cc][f+2];
    }
    float s = a, ss = a * a;
    #pragma unroll
    for (int m = 16; m >= 1; m >>= 1) { s += __shfl_xor(s, m); ss += __shfl_xor(ss, m); }
    float mu = s * (1.f/32.f), rs = rsqrtf(ss * (1.f/32.f) - mu*mu + 1e-5f);
    float v = fmaxf((a - mu) * rs * g1[f] + be1[f], 0.f);
    s_x1[c][1 + f] = v;
    x1g[(size_t)bt * 256 + tid] = f2bf(v);
  }
  if (tid < 8) { s_x1[tid][0] = 0.f; s_x1[tid][33] = 0.f; }
  __syncthreads();

  // q/k/v convs (8->64 each)
  {
    int h = tid >> 2, fg = tid & 3;
    float aq[8], ak[8], av[8];
    float qbv = qb[h], kbv = kb[h], vbv = vb[h];
    #pragma unroll
    for (int i = 0; i < 8; ++i) { aq[i] = qbv; ak[i] = kbv; av[i] = vbv; }
    #pragma unroll
    for (int c = 0; c < 8; ++c) {
      const float* qr = qw + (h * 8 + c) * 3;
      const float* kr = kw + (h * 8 + c) * 3;
      const float* vr = vw + (h * 8 + c) * 3;
      float q0 = qr[0], q1 = qr[1], q2 = qr[2];
      float k0 = kr[0], k1 = kr[1], k2 = kr[2];
      float v0 = vr[0], v1 = vr[1], v2 = vr[2];
      #pragma unroll
      for (int i = 0; i < 8; ++i) {
        int f = fg + i * 4;
        float xa = s_x1[c][f], xb = s_x1[c][f+1], xc = s_x1[c][f+2];
        aq[i] += q0*xa + q1*xb + q2*xc;
        ak[i] += k0*xa + k1*xb + k2*xc;
        av[i] += v0*xa + v1*xb + v2*xc;
      }
    }
    #pragma unroll
    for (int i = 0; i < 8; ++i) {
      int f = fg + i * 4;
      s_q[h][f] = aq[i];
      s_k[h][f] = ak[i];
      s_v[f][h] = av[i];
    }
  }
  __syncthreads();

  // scores
  const int sf = tid >> 3, sgq = tid & 7;
  float sc0 = 0.f, sc1 = 0.f, sc2 = 0.f, sc3 = 0.f;
  #pragma unroll 8
  for (int h = 0; h < 64; ++h) {
    float q = s_q[h][sf];
    float4 k4 = *(const float4*)&s_k[h][sgq * 4];
    sc0 += q * k4.x; sc1 += q * k4.y; sc2 += q * k4.z; sc3 += q * k4.w;
  }
  sc0 *= 0.125f; sc1 *= 0.125f; sc2 *= 0.125f; sc3 *= 0.125f;
  float mx = fmaxf(fmaxf(sc0, sc1), fmaxf(sc2, sc3));
  #pragma unroll
  for (int m = 32; m >= 1; m >>= 1) mx = fmaxf(mx, __shfl_xor(mx, m));
  if ((tid & 63) == 0) s_red[tid >> 6] = mx;
  __syncthreads();
  mx = fmaxf(fmaxf(s_red[0], s_red[1]), fmaxf(s_red[2], s_red[3]));
  sc0 = __expf(sc0 - mx); sc1 = __expf(sc1 - mx);
  sc2 = __expf(sc2 - mx); sc3 = __expf(sc3 - mx);
  float sm = sc0 + sc1 + sc2 + sc3;
  #pragma unroll
  for (int m = 32; m >= 1; m >>= 1) sm += __shfl_xor(sm, m);
  __syncthreads();
  if ((tid & 63) == 0) s_red[4 + (tid >> 6)] = sm;
  __syncthreads();
  float inv = 1.f / (s_red[4] + s_red[5] + s_red[6] + s_red[7]);
  {
    float4 o4; o4.x = sc0 * inv; o4.y = sc1 * inv; o4.z = sc2 * inv; o4.w = sc3 * inv;
    *(float4*)&s_sc[sf][sgq * 4] = o4;
  }
  __syncthreads();

  // att
  {
    const int f = tid >> 3, hq = tid & 7;
    float a0=0,a1=0,a2=0,a3=0,a4=0,a5=0,a6=0,a7=0;
    #pragma unroll 8
    for (int g = 0; g < 32; ++g) {
      float w = s_sc[f][g];
      float4 v0 = *(const float4*)&s_v[g][hq * 8];
      float4 v1 = *(const float4*)&s_v[g][hq * 8 + 4];
      a0 += w * v0.x; a1 += w * v0.y; a2 += w * v0.z; a3 += w * v0.w;
      a4 += w * v1.x; a5 += w * v1.y; a6 += w * v1.z; a7 += w * v1.w;
    }
    u16x8 ov;
    ov[0] = f2bf(a0); ov[1] = f2bf(a1); ov[2] = f2bf(a2); ov[3] = f2bf(a3);
    ov[4] = f2bf(a4); ov[5] = f2bf(a5); ov[6] = f2bf(a6); ov[7] = f2bf(a7);
    *(u16x8*)(gi + (size_t)blockIdx.x * 2048 + f * 64 + hq * 8) = ov;
  }
}

// ---------------------------------------------------------------------------
// K2: MFMA GEMM (unchanged)
// ---------------------------------------------------------------------------
__global__ __launch_bounds__(512, 2) void k_gemm_mfma(
    const u16* __restrict__ A, const u16* __restrict__ Wb,
    const float* __restrict__ bias, u16* __restrict__ C, int M)
{
  __shared__ u16 lA[128][40];
  __shared__ u16 lB[256][40];
  const int tid = threadIdx.x;
  const int m0 = blockIdx.x * 128, n0 = blockIdx.y * 256;
  const int w = tid >> 6, l = tid & 63;
  const int wr = w >> 2, wc = w & 3;
  const int fr = l & 15, fg = l >> 4;
  f32x4 acc[4][4] = {};
  const int ar = tid >> 2, akc = tid & 3;
  const int br = tid >> 1, bkc = tid & 1;
  for (int k0 = 0; k0 < 2048; k0 += 32) {
    int am = m0 + ar;
    u16x8 av = (u16x8)(u16)0;
    if (am < M) av = *(const u16x8*)(A + (size_t)am * 2048 + k0 + akc * 8);
    *(u16x8*)&lA[ar][akc * 8] = av;
    const u16* bp = Wb + (size_t)(n0 + br) * 2048 + k0 + bkc * 16;
    u16x8 bv0 = *(const u16x8*)bp;
    u16x8 bv1 = *(const u16x8*)(bp + 8);
    *(u16x8*)&lB[br][bkc * 16] = bv0;
    *(u16x8*)&lB[br][bkc * 16 + 8] = bv1;
    __syncthreads();
    #pragma unroll
    for (int mi = 0; mi < 4; ++mi) {
      s16x8 afr = *(const s16x8*)&lA[wr * 64 + mi * 16 + fr][fg * 8];
      #pragma unroll
      for (int ni = 0; ni < 4; ++ni) {
        s16x8 bfr = *(const s16x8*)&lB[wc * 64 + ni * 16 + fr][fg * 8];
        acc[mi][ni] = __builtin_amdgcn_mfma_f32_16x16x32_bf16(afr, bfr, acc[mi][ni], 0, 0, 0);
      }
    }
    __syncthreads();
  }
  #pragma unroll
  for (int mi = 0; mi < 4; ++mi) {
    #pragma unroll
    for (int ni = 0; ni < 4; ++ni) {
      int col = n0 + wc * 64 + ni * 16 + (l & 15);
      float bv = bias[col];
      #pragma unroll
      for (int i = 0; i < 4; ++i) {
        int row = m0 + wr * 64 + mi * 16 + (l >> 4) * 4 + i;
        if (row < M) C[(size_t)row * 768 + col] = f2bf(acc[mi][ni][i] + bv);
      }
    }
  }
}

// ---------------------------------------------------------------------------
// K3: main GRU over T=1000. 1024 thr/block (4 waves/SIMD), one block per b.
//     4-way k-split: thread (u=tid>>2, part=tid&3) owns 64-wide k-slice of
//     gate rows {u, 256+u, 512+u} as packed f16. SSA-sunk streaming loads
//     (12 uint4) + 96 fdot2 per thread per step; shfl_xor(1,2) reduce.
// ---------------------------------------------------------------------------
#define LD16(V, P, Q) { \
  uint4 a_ = (P)[(Q)*4+0], b_ = (P)[(Q)*4+1], c_ = (P)[(Q)*4+2], d_ = (P)[(Q)*4+3]; \
  V[0]=a_.x; V[1]=a_.y; V[2]=a_.z; V[3]=a_.w; \
  V[4]=b_.x; V[5]=b_.y; V[6]=b_.z; V[7]=b_.w; \
  V[8]=c_.x; V[9]=c_.y; V[10]=c_.z; V[11]=c_.w; \
  V[12]=d_.x; V[13]=d_.y; V[14]=d_.z; V[15]=d_.w; }

#define D1(H, W, E, acc) acc = __builtin_amdgcn_fdot2((H), bch((W)[E]), (acc), false);
#define BLK(C, WR, WZ, WN, E) { \
  uint4 hv_ = hp[C]; \
  h2t h0_ = bch(hv_.x), h1_ = bch(hv_.y), h2_ = bch(hv_.z), h3_ = bch(hv_.w); \
  D1(h0_, WR, (E)+0, pr0) D1(h0_, WZ, (E)+0, pz0) D1(h0_, WN, (E)+0, pn0) \
  D1(h1_, WR, (E)+1, pr1) D1(h1_, WZ, (E)+1, pz1) D1(h1_, WN, (E)+1, pn1) \
  D1(h2_, WR, (E)+2, pr0) D1(h2_, WZ, (E)+2, pz0) D1(h2_, WN, (E)+2, pn0) \
  D1(h3_, WR, (E)+3, pr1) D1(h3_, WZ, (E)+3, pz1) D1(h3_, WN, (E)+3, pn1) }

__global__ __launch_bounds__(1024) void k_gru_batch(
    const u16* __restrict__ gih, const unsigned* __restrict__ wpk,
    const float* __restrict__ bhh, u16* __restrict__ ob,
    float* __restrict__ hatt, int b0)
{
  __shared__ h2t s_h2[2][128];
  const int tid = threadIdx.x;
  const int u = tid >> 2, part = tid & 3;
  const int bl = blockIdx.x;
  const int b = b0 + bl;

  // packed rows: wpk[(g*256+u)*128 + part*32 + j], j in [0,32) u32
  const uint4* wr4 = (const uint4*)(wpk + ((size_t)(      u) * 128) + part * 32);
  const uint4* wz4 = (const uint4*)(wpk + ((size_t)(256 + u) * 128) + part * 32);
  const uint4* wn4 = (const uint4*)(wpk + ((size_t)(512 + u) * 128) + part * 32);

  // SSA weight vectors (outside the loop; compiler sinks the loads)
  u32x16 wr0, wr1, wz0, wz1, wn0, wn1;
  LD16(wr0, wr4, 0) LD16(wr1, wr4, 1)
  LD16(wz0, wz4, 0) LD16(wz1, wz4, 1)
  LD16(wn0, wn4, 0) LD16(wn1, wn4, 1)

  float bh_r = 0.f, bh_z = 0.f, bh_n = 0.f;
  if (part == 0) { bh_r = bhh[u]; bh_z = bhh[256 + u]; bh_n = bhh[512 + u]; }
  if (tid < 128) s_h2[0][tid] = pk(0.f, 0.f);
  __syncthreads();

  float hprev = 0.f;
  int cur = 0;
  for (int t = 0; t < 1000; ++t) {
    float gi_r = 0.f, gi_z = 0.f, gi_n = 0.f;
    if (part == 0) {
      const u16* gr_ = gih + ((size_t)bl * 1000 + t) * 768;
      gi_r = bf2f(gr_[u]); gi_z = bf2f(gr_[256 + u]); gi_n = bf2f(gr_[512 + u]);
    }
    const uint4* hp = (const uint4*)&s_h2[cur][part * 32];
    float pr0 = 0.f, pr1 = 0.f, pz0 = 0.f, pz1 = 0.f, pn0 = 0.f, pn1 = 0.f;
    BLK(0, wr0, wz0, wn0,  0) BLK(1, wr0, wz0, wn0,  4)
    BLK(2, wr0, wz0, wn0,  8) BLK(3, wr0, wz0, wn0, 12)
    BLK(4, wr1, wz1, wn1,  0) BLK(5, wr1, wz1, wn1,  4)
    BLK(6, wr1, wz1, wn1,  8) BLK(7, wr1, wz1, wn1, 12)
    float pr = pr0 + pr1, pz = pz0 + pz1, pn = pn0 + pn1;
    pr += __shfl_xor(pr, 1); pr += __shfl_xor(pr, 2);
    pz += __shfl_xor(pz, 1); pz += __shfl_xor(pz, 2);
    pn += __shfl_xor(pn, 1); pn += __shfl_xor(pn, 2);
    float hnew = 0.f;
    if (part == 0) {
      float r = sigf(gi_r + pr + bh_r);
      float z = sigf(gi_z + pz + bh_z);
      float n = tanhfast(gi_n + r * (pn + bh_n));
      hnew = (1.f - z) * n + z * hprev;
      hprev = hnew;
      ob[((size_t)b * 1000 + t) * 256 + u] = f2bf(hnew);
      if (t == 999) hatt[b * 256 + u] = hnew;
    }
    // pack (h[u], h[u+1]): writer tid%8==0 pairs with lane tid+4 (u+1, part0)
    float hother = __shfl_xor(hnew, 4);
    if ((tid & 7) == 0) s_h2[cur ^ 1][tid >> 3] = pk(hnew, hother);
    __syncthreads();
    cur ^= 1;
  }
}

// ---------------------------------------------------------------------------
// K4: snr GRU (unchanged)
// ---------------------------------------------------------------------------
__global__ __launch_bounds__(256) void k_gru_snr(
    const u16* __restrict__ ob, const float* __restrict__ wih,
    const float* __restrict__ whh, const float* __restrict__ bih,
    const float* __restrict__ bhh, const float* __restrict__ fcw,
    const float* __restrict__ fcb,
    float* __restrict__ lsnr_out, float* __restrict__ hsnr_out)
{
  __shared__ float s_wi[48][260];
  __shared__ float s_wh[48][20];
  __shared__ float s_o[16][260];
  __shared__ float s_h[16][20];
  const int tid = threadIdx.x, wg = blockIdx.x;
  const int n0 = wg * 16;
  for (int i = tid; i < 48 * 256; i += 256) s_wi[i >> 8][i & 255] = wih[i];
  for (int i = tid; i < 768; i += 256) s_wh[i >> 4][i & 15] = whh[i];
  const int n = tid >> 4, u = tid & 15;
  const bool valid = (n0 + n) < 1000;
  s_h[n][u] = 0.f;
  float hcur = 0.f;
  const float bi_r = bih[u], bi_z = bih[16 + u], bi_n = bih[32 + u];
  const float bh_r = bhh[u], bh_z = bhh[16 + u], bh_n = bhh[32 + u];
  const float fw = fcw[u], fb = fcb[0];
  __syncthreads();
  for (int step = 0; step < 32; ++step) {
    for (int i = tid; i < 512; i += 256) {
      int nn = i >> 5, c8 = (i & 31) * 8;
      int row = n0 + nn;
      if (row < 1000) {
        u16x8 v = *(const u16x8*)(ob + ((size_t)step * 1000 + row) * 256 + c8);
        #pragma unroll
        for (int j = 0; j < 8; ++j) s_o[nn][c8 + j] = bf2f(v[j]);
      } else {
        #pragma unroll
        for (int j = 0; j < 8; ++j) s_o[nn][c8 + j] = 0.f;
      }
    }
    __syncthreads();
    float gr = bi_r, gz = bi_z, gn = bi_n;
    {
      const float4* o4 = (const float4*)&s_o[n][0];
      const float4* wr = (const float4*)&s_wi[u][0];
      const float4* wz = (const float4*)&s_wi[16 + u][0];
      const float4* wn = (const float4*)&s_wi[32 + u][0];
      #pragma unroll 4
      for (int k4 = 0; k4 < 64; ++k4) {
        float4 ov = o4[k4];
        float4 a = wr[k4], c = wz[k4], d = wn[k4];
        gr += ov.x*a.x + ov.y*a.y + ov.z*a.z + ov.w*a.w;
        gz += ov.x*c.x + ov.y*c.y + ov.z*c.z + ov.w*c.w;
        gn += ov.x*d.x + ov.y*d.y + ov.z*d.z + ov.w*d.w;
      }
    }
    float hr = bh_r, hz = bh_z, hn_ = bh_n;
    #pragma unroll
    for (int k = 0; k < 16; ++k) {
      float hv = s_h[n][k];
      hr  += s_wh[u][k] * hv;
      hz  += s_wh[16 + u][k] * hv;
      hn_ += s_wh[32 + u][k] * hv;
    }
    float r = sigf(gr + hr);
    float z = sigf(gz + hz);
    float nn2 = tanhfast(gn + r * hn_);
    float hnew = (1.f - z) * nn2 + z * hcur;
    __syncthreads();
    s_h[n][u] = hnew;
    hcur = hnew;
    float part = hnew * fw;
    #pragma unroll
    for (int m = 8; m >= 1; m >>= 1) part += __shfl_xor(part, m);
    if (u == 0 && valid) lsnr_out[step * 1000 + n0 + n] = sigf(part + fb) * 50.f - 15.f;
    __syncthreads();
  }
  if (valid) hsnr_out[(size_t)(n0 + n) * 16 + u] = hcur;
}

// ---------------------------------------------------------------------------
// K5: final (unchanged)
// ---------------------------------------------------------------------------
__global__ __launch_bounds__(256) void k_final(
    const u16* __restrict__ x1g, const u16* __restrict__ ob,
    const float* __restrict__ lng, const float* __restrict__ lnb,
    const float* __restrict__ c2w, const float* __restrict__ c2b,
    const float* __restrict__ g2, const float* __restrict__ be2,
    float* __restrict__ m_out)
{
  const int bt = blockIdx.x, tid = threadIdx.x;
  __shared__ float s_xe[8][34];
  __shared__ float s_y[32];
  const int c = tid >> 5, f = tid & 31;
  float v = bf2f(x1g[(size_t)bt * 256 + tid]) + bf2f(ob[(size_t)bt * 256 + tid]);
  float s = v, ss = v * v;
  #pragma unroll
  for (int m = 16; m >= 1; m >>= 1) { s += __shfl_xor(s, m); ss += __shfl_xor(ss, m); }
  float mu = s * (1.f/32.f), rs = rsqrtf(ss * (1.f/32.f) - mu * mu + 1e-5f);
  s_xe[c][1 + f] = (v - mu) * rs * lng[f] + lnb[f];
  if (tid < 8) { s_xe[tid][0] = 0.f; s_xe[tid][33] = 0.f; }
  __syncthreads();
  if (tid < 32) {
    float a = c2b[0];
    #pragma unroll
    for (int cc = 0; cc < 8; ++cc) {
      const float* wr = c2w + cc * 3;
      a += wr[0]*s_xe[cc][tid] + wr[1]*s_xe[cc][tid+1] + wr[2]*s_xe[cc][tid+2];
    }
    s_y[tid] = a;
  }
  __syncthreads();
  if (tid < 32) {
    float y = s_y[tid];
    float s2 = y, ss2 = y * y;
    #pragma unroll
    for (int m = 16; m >= 1; m >>= 1) { s2 += __shfl_xor(s2, m); ss2 += __shfl_xor(ss2, m); }
    float mu2 = s2 * (1.f/32.f), rs2 = rsqrtf(ss2 * (1.f/32.f) - mu2 * mu2 + 1e-5f);
    float yn = (y - mu2) * rs2 * g2[tid] + be2[tid];
    m_out[(size_t)bt * 32 + tid] = sigf(yn);
  }
}

// ---------------------------------------------------------------------------
extern "C" void kernel_launch(void* const* d_in, const int* in_sizes, int n_in,
                              void* d_out, int out_size, void* d_ws, size_t ws_size,
                              hipStream_t stream)
{
  const float* input = (const float*)d_in[0];
  const float* w0    = (const float*)d_in[1];
  const float* b0    = (const float*)d_in[2];
  const float* ln0g  = (const float*)d_in[3];
  const float* ln0b  = (const float*)d_in[4];
  const float* w1    = (const float*)d_in[5];
  const float* b1    = (const float*)d_in[6];
  const float* ln1g  = (const float*)d_in[7];
  const float* ln1b  = (const float*)d_in[8];
  const float* qw    = (const float*)d_in[9];
  const float* qb    = (const float*)d_in[10];
  const float* kw    = (const float*)d_in[11];
  const float* kb    = (const float*)d_in[12];
  const float* vw    = (const float*)d_in[13];
  const float* vb    = (const float*)d_in[14];
  const float* gwih  = (const float*)d_in[15];
  const float* gwhh  = (const float*)d_in[16];
  const float* gbih  = (const float*)d_in[17];
  const float* gbhh  = (const float*)d_in[18];
  const float* lng   = (const float*)d_in[19];
  const float* lnb   = (const float*)d_in[20];
  const float* swih  = (const float*)d_in[21];
  const float* swhh  = (const float*)d_in[22];
  const float* sbih  = (const float*)d_in[23];
  const float* sbhh  = (const float*)d_in[24];
  const float* fcw   = (const float*)d_in[25];
  const float* fcb   = (const float*)d_in[26];
  const float* c2w   = (const float*)d_in[27];
  const float* c2b   = (const float*)d_in[28];
  const float* ln2g  = (const float*)d_in[29];
  const float* ln2b  = (const float*)d_in[30];
  (void)in_sizes; (void)n_in; (void)out_size;

  char* ws = (char*)d_ws;
  size_t off = 0;
  auto take = [&](size_t bytes) -> void* {
    void* p = ws + off;
    off += (bytes + 255) & ~(size_t)255;
    return p;
  };
  u16* x1g      = (u16*)take((size_t)32000 * 256 * 2);
  u16* ob       = (u16*)take((size_t)32000 * 256 * 2);
  u16* gwb      = (u16*)take((size_t)768 * 2048 * 2);     // bf16 gruo_wih
  unsigned* wpk = (unsigned*)take((size_t)768 * 128 * 4); // packed f16 whh

  const size_t fixedoff = off;
  int GB = 32;
  while (GB > 1) {
    int ch = 6400; if (ch > GB * 1000) ch = ((GB * 1000 + 63) / 64) * 64;
    size_t need = fixedoff + ((size_t)GB * 1000 * 768 * 2 + 256)
                           + ((size_t)ch * 2048 * 2 + 256);
    if (need <= ws_size) break;
    GB >>= 1;
  }
  int CH = 6400; if (CH > GB * 1000) CH = ((GB * 1000 + 63) / 64) * 64;
  u16* gih = (u16*)take((size_t)GB * 1000 * 768 * 2);
  u16* gi  = (u16*)take((size_t)CH * 2048 * 2);

  float* out      = (float*)d_out;
  float* m_out    = out;                 // [32,1,1000,32] = 1,024,000
  float* lsnr_out = out + 1024000;       // [32,1000,1]    =    32,000
  float* hatt_out = out + 1056000;       // [1,32,256]     =     8,192
  float* hsnr_out = out + 1064192;       // [1,1000,16]    =    16,000

  k_wcvt<<<768, 256, 0, stream>>>(gwih, gwb);
  k_wcvt2<<<384, 256, 0, stream>>>(gwhh, wpk);

  const int NG = 32 / GB;
  for (int g = 0; g < NG; ++g) {
    const int row0 = g * GB * 1000, rows = GB * 1000;
    for (int c0 = 0; c0 < rows; c0 += CH) {
      const int Mc = (rows - c0 < CH) ? (rows - c0) : CH;
      k_frontend<<<Mc, 256, 0, stream>>>(input, w0, b0, ln0g, ln0b, w1, b1,
                                         ln1g, ln1b, qw, qb, kw, kb, vw, vb,
                                         row0 + c0, x1g, gi);
      dim3 gg((Mc + 127) / 128, 3);
      k_gemm_mfma<<<gg, 512, 0, stream>>>(gi, gwb, gbih, gih + (size_t)c0 * 768, Mc);
    }
    k_gru_batch<<<GB, 1024, 0, stream>>>(gih, wpk, gbhh, ob, hatt_out, g * GB);
  }
  k_gru_snr<<<64, 256, 0, stream>>>(ob, swih, swhh, sbih, sbhh, fcw, fcb,
                                    lsnr_out, hsnr_out);
  k_final<<<32000, 256, 0, stream>>>(x1g, ob, lng, lnb, c2w, c2b, ln2g, ln2b, m_out);
}

// Round 14
// 2231.076 us; speedup vs baseline: 1.2294x; 1.2294x over previous
//
#include <hip/hip_runtime.h>

// ErbStage: conv0+LN+ReLU -> conv1+LN+ReLU -> spectral attention -> GRU(T=1000)
//           -> GRU(B=32 scan) + lsnr -> LN/conv2/LN/sigmoid mask.
//
// R14: (a) GRU reverted to R12's proven best (512 thr, 2-way k-split,
//          SSA-sunk packed-f16 streaming, 1,473us). GRU is pinned at
//          ~1.47us/step by per-step serial latency (bytes/regs/waves all
//          falsified as levers in R5-R13) — frozen.
//      (b) frontend+GEMM de-chunked: one frontend launch (32000 blocks) and
//          one GEMM launch (250x3=750 blocks, ~100% occupancy vs 59% at
//          CH=6400), ws permitting (adaptive CH fallback retained).

typedef unsigned short u16;
typedef u16 u16x8 __attribute__((ext_vector_type(8)));
typedef short s16x8 __attribute__((ext_vector_type(8)));
typedef float f32x4 __attribute__((ext_vector_type(4)));
typedef _Float16 h2t __attribute__((ext_vector_type(2)));
typedef unsigned int u32x16 __attribute__((ext_vector_type(16)));

__device__ __forceinline__ float sigf(float x) { return 1.f / (1.f + __expf(-x)); }
__device__ __forceinline__ float tanhfast(float x) { return 2.f / (1.f + __expf(-2.f * x)) - 1.f; }
__device__ __forceinline__ float bf2f(u16 s) { union { unsigned u; float f; } x; x.u = ((unsigned)s) << 16; return x.f; }
__device__ __forceinline__ u16 f2bf(float f) {
  union { float f; unsigned u; } x; x.f = f;
  unsigned r = x.u + 0x7fffu + ((x.u >> 16) & 1u);
  return (u16)(r >> 16);
}
__device__ __forceinline__ h2t pk(float a, float b) {
  auto v = __builtin_amdgcn_cvt_pkrtz(a, b);
  union { decltype(v) i; h2t o; } u; u.i = v; return u.o;
}
__device__ __forceinline__ h2t bch(unsigned x) { return __builtin_bit_cast(h2t, x); }

// ---------------------------------------------------------------------------
// K0a: one-time W f32 -> bf16 convert (for MFMA GEMM)
// ---------------------------------------------------------------------------
__global__ __launch_bounds__(256) void k_wcvt(const float* __restrict__ W,
                                              u16* __restrict__ Wb)
{
  const size_t i = ((size_t)blockIdx.x * 256 + threadIdx.x) * 8;
  float4 a = *(const float4*)(W + i);
  float4 b = *(const float4*)(W + i + 4);
  u16x8 o;
  o[0] = f2bf(a.x); o[1] = f2bf(a.y); o[2] = f2bf(a.z); o[3] = f2bf(a.w);
  o[4] = f2bf(b.x); o[5] = f2bf(b.y); o[6] = f2bf(b.z); o[7] = f2bf(b.w);
  *(u16x8*)(Wb + i) = o;
}

// ---------------------------------------------------------------------------
// K0b: one-time whh f32 -> packed f16 pairs
// ---------------------------------------------------------------------------
__global__ __launch_bounds__(256) void k_wcvt2(const float* __restrict__ W,
                                               unsigned* __restrict__ Wp)
{
  const size_t i = (size_t)blockIdx.x * 256 + threadIdx.x;   // 98304 u32
  float2 a = *(const float2*)(W + i * 2);
  Wp[i] = __builtin_bit_cast(unsigned, pk(a.x, a.y));
}

// ---------------------------------------------------------------------------
// K1: fused frontend per (b,t)
// ---------------------------------------------------------------------------
__global__ __launch_bounds__(256) void k_frontend(
    const float* __restrict__ in,
    const float* __restrict__ w0c, const float* __restrict__ b0c,
    const float* __restrict__ g0, const float* __restrict__ be0,
    const float* __restrict__ w1c, const float* __restrict__ b1c,
    const float* __restrict__ g1, const float* __restrict__ be1,
    const float* __restrict__ qw, const float* __restrict__ qb,
    const float* __restrict__ kw, const float* __restrict__ kb,
    const float* __restrict__ vw, const float* __restrict__ vb,
    int bt0, u16* __restrict__ x1g, u16* __restrict__ gi)
{
  const int bt = bt0 + blockIdx.x, tid = threadIdx.x;
  __shared__ float s_in[34];
  __shared__ float s_x0[16][34];
  __shared__ float s_x1[8][34];
  __shared__ float s_q[64][36];
  __shared__ float s_k[64][36];
  __shared__ float s_v[32][68];
  __shared__ float s_sc[32][36];
  __shared__ float s_red[8];
  __shared__ float s_mu[16], s_rs[16];

  if (tid < 32) s_in[1 + tid] = in[(size_t)bt * 32 + tid];
  if (tid == 0) { s_in[0] = 0.f; s_in[33] = 0.f; }
  __syncthreads();

  // conv0 (1->16)
  #pragma unroll
  for (int i = 0; i < 2; ++i) {
    int o = tid + i * 256, c = o >> 5, f = o & 31;
    float a = b0c[c] + w0c[c*3]*s_in[f] + w0c[c*3+1]*s_in[f+1] + w0c[c*3+2]*s_in[f+2];
    s_x0[c][1 + f] = a;
  }
  __syncthreads();
  {
    int c = tid >> 4, i = tid & 15;
    float a = s_x0[c][1 + i], b = s_x0[c][17 + i];
    float s = a + b, ss = a * a + b * b;
    #pragma unroll
    for (int m = 8; m >= 1; m >>= 1) { s += __shfl_xor(s, m); ss += __shfl_xor(ss, m); }
    if (i == 0) { float mu = s * (1.f/32.f); s_mu[c] = mu; s_rs[c] = rsqrtf(ss * (1.f/32.f) - mu*mu + 1e-5f); }
  }
  __syncthreads();
  #pragma unroll
  for (int i = 0; i < 2; ++i) {
    int o = tid + i * 256, c = o >> 5, f = o & 31;
    float v = (s_x0[c][1 + f] - s_mu[c]) * s_rs[c] * g0[f] + be0[f];
    s_x0[c][1 + f] = fmaxf(v, 0.f);
  }
  if (tid < 16) { s_x0[tid][0] = 0.f; s_x0[tid][33] = 0.f; }
  __syncthreads();

  // conv1 (16->8) + ln1 + relu
  {
    int c = tid >> 5, f = tid & 31;
    float a = b1c[c];
    #pragma unroll
    for (int cc = 0; cc < 16; ++cc) {
      const float* wr = w1c + (c * 16 + cc) * 3;
      a += wr[0]*s_x0[cc][f] + wr[1]*s_x0[cc][f+1] + wr[2]*s_x0[cc][f+2];
    }
    float s = a, ss = a * a;
    #pragma unroll
    for (int m = 16; m >= 1; m >>= 1) { s += __shfl_xor(s, m); ss += __shfl_xor(ss, m); }
    float mu = s * (1.f/32.f), rs = rsqrtf(ss * (1.f/32.f) - mu*mu + 1e-5f);
    float v = fmaxf((a - mu) * rs * g1[f] + be1[f], 0.f);
    s_x1[c][1 + f] = v;
    x1g[(size_t)bt * 256 + tid] = f2bf(v);
  }
  if (tid < 8) { s_x1[tid][0] = 0.f; s_x1[tid][33] = 0.f; }
  __syncthreads();

  // q/k/v convs (8->64 each)
  {
    int h = tid >> 2, fg = tid & 3;
    float aq[8], ak[8], av[8];
    float qbv = qb[h], kbv = kb[h], vbv = vb[h];
    #pragma unroll
    for (int i = 0; i < 8; ++i) { aq[i] = qbv; ak[i] = kbv; av[i] = vbv; }
    #pragma unroll
    for (int c = 0; c < 8; ++c) {
      const float* qr = qw + (h * 8 + c) * 3;
      const float* kr = kw + (h * 8 + c) * 3;
      const float* vr = vw + (h * 8 + c) * 3;
      float q0 = qr[0], q1 = qr[1], q2 = qr[2];
      float k0 = kr[0], k1 = kr[1], k2 = kr[2];
      float v0 = vr[0], v1 = vr[1], v2 = vr[2];
      #pragma unroll
      for (int i = 0; i < 8; ++i) {
        int f = fg + i * 4;
        float xa = s_x1[c][f], xb = s_x1[c][f+1], xc = s_x1[c][f+2];
        aq[i] += q0*xa + q1*xb + q2*xc;
        ak[i] += k0*xa + k1*xb + k2*xc;
        av[i] += v0*xa + v1*xb + v2*xc;
      }
    }
    #pragma unroll
    for (int i = 0; i < 8; ++i) {
      int f = fg + i * 4;
      s_q[h][f] = aq[i];
      s_k[h][f] = ak[i];
      s_v[f][h] = av[i];
    }
  }
  __syncthreads();

  // scores
  const int sf = tid >> 3, sgq = tid & 7;
  float sc0 = 0.f, sc1 = 0.f, sc2 = 0.f, sc3 = 0.f;
  #pragma unroll 8
  for (int h = 0; h < 64; ++h) {
    float q = s_q[h][sf];
    float4 k4 = *(const float4*)&s_k[h][sgq * 4];
    sc0 += q * k4.x; sc1 += q * k4.y; sc2 += q * k4.z; sc3 += q * k4.w;
  }
  sc0 *= 0.125f; sc1 *= 0.125f; sc2 *= 0.125f; sc3 *= 0.125f;
  float mx = fmaxf(fmaxf(sc0, sc1), fmaxf(sc2, sc3));
  #pragma unroll
  for (int m = 32; m >= 1; m >>= 1) mx = fmaxf(mx, __shfl_xor(mx, m));
  if ((tid & 63) == 0) s_red[tid >> 6] = mx;
  __syncthreads();
  mx = fmaxf(fmaxf(s_red[0], s_red[1]), fmaxf(s_red[2], s_red[3]));
  sc0 = __expf(sc0 - mx); sc1 = __expf(sc1 - mx);
  sc2 = __expf(sc2 - mx); sc3 = __expf(sc3 - mx);
  float sm = sc0 + sc1 + sc2 + sc3;
  #pragma unroll
  for (int m = 32; m >= 1; m >>= 1) sm += __shfl_xor(sm, m);
  __syncthreads();
  if ((tid & 63) == 0) s_red[4 + (tid >> 6)] = sm;
  __syncthreads();
  float inv = 1.f / (s_red[4] + s_red[5] + s_red[6] + s_red[7]);
  {
    float4 o4; o4.x = sc0 * inv; o4.y = sc1 * inv; o4.z = sc2 * inv; o4.w = sc3 * inv;
    *(float4*)&s_sc[sf][sgq * 4] = o4;
  }
  __syncthreads();

  // att
  {
    const int f = tid >> 3, hq = tid & 7;
    float a0=0,a1=0,a2=0,a3=0,a4=0,a5=0,a6=0,a7=0;
    #pragma unroll 8
    for (int g = 0; g < 32; ++g) {
      float w = s_sc[f][g];
      float4 v0 = *(const float4*)&s_v[g][hq * 8];
      float4 v1 = *(const float4*)&s_v[g][hq * 8 + 4];
      a0 += w * v0.x; a1 += w * v0.y; a2 += w * v0.z; a3 += w * v0.w;
      a4 += w * v1.x; a5 += w * v1.y; a6 += w * v1.z; a7 += w * v1.w;
    }
    u16x8 ov;
    ov[0] = f2bf(a0); ov[1] = f2bf(a1); ov[2] = f2bf(a2); ov[3] = f2bf(a3);
    ov[4] = f2bf(a4); ov[5] = f2bf(a5); ov[6] = f2bf(a6); ov[7] = f2bf(a7);
    *(u16x8*)(gi + (size_t)blockIdx.x * 2048 + f * 64 + hq * 8) = ov;
  }
}

// ---------------------------------------------------------------------------
// K2: MFMA GEMM: C[M,768](bf16) = A[M,2048](bf16) @ Wb[768,2048]^T + bias
// ---------------------------------------------------------------------------
__global__ __launch_bounds__(512, 2) void k_gemm_mfma(
    const u16* __restrict__ A, const u16* __restrict__ Wb,
    const float* __restrict__ bias, u16* __restrict__ C, int M)
{
  __shared__ u16 lA[128][40];
  __shared__ u16 lB[256][40];
  const int tid = threadIdx.x;
  const int m0 = blockIdx.x * 128, n0 = blockIdx.y * 256;
  const int w = tid >> 6, l = tid & 63;
  const int wr = w >> 2, wc = w & 3;
  const int fr = l & 15, fg = l >> 4;
  f32x4 acc[4][4] = {};
  const int ar = tid >> 2, akc = tid & 3;
  const int br = tid >> 1, bkc = tid & 1;
  for (int k0 = 0; k0 < 2048; k0 += 32) {
    int am = m0 + ar;
    u16x8 av = (u16x8)(u16)0;
    if (am < M) av = *(const u16x8*)(A + (size_t)am * 2048 + k0 + akc * 8);
    *(u16x8*)&lA[ar][akc * 8] = av;
    const u16* bp = Wb + (size_t)(n0 + br) * 2048 + k0 + bkc * 16;
    u16x8 bv0 = *(const u16x8*)bp;
    u16x8 bv1 = *(const u16x8*)(bp + 8);
    *(u16x8*)&lB[br][bkc * 16] = bv0;
    *(u16x8*)&lB[br][bkc * 16 + 8] = bv1;
    __syncthreads();
    #pragma unroll
    for (int mi = 0; mi < 4; ++mi) {
      s16x8 afr = *(const s16x8*)&lA[wr * 64 + mi * 16 + fr][fg * 8];
      #pragma unroll
      for (int ni = 0; ni < 4; ++ni) {
        s16x8 bfr = *(const s16x8*)&lB[wc * 64 + ni * 16 + fr][fg * 8];
        acc[mi][ni] = __builtin_amdgcn_mfma_f32_16x16x32_bf16(afr, bfr, acc[mi][ni], 0, 0, 0);
      }
    }
    __syncthreads();
  }
  #pragma unroll
  for (int mi = 0; mi < 4; ++mi) {
    #pragma unroll
    for (int ni = 0; ni < 4; ++ni) {
      int col = n0 + wc * 64 + ni * 16 + (l & 15);
      float bv = bias[col];
      #pragma unroll
      for (int i = 0; i < 4; ++i) {
        int row = m0 + wr * 64 + mi * 16 + (l >> 4) * 4 + i;
        if (row < M) C[(size_t)row * 768 + col] = f2bf(acc[mi][ni][i] + bv);
      }
    }
  }
}

// ---------------------------------------------------------------------------
// K3: main GRU over T=1000 (R12's proven config — FROZEN).
//     512 thr/block, one block per batch element. Packed-f16 weights as SSA
//     u32x16 vectors assembled OUTSIDE the t-loop; the compiler sinks the 36
//     uint4 loads into the loop and bulk-schedules them (pipelined stream).
//     Thread (u=tid>>1, part=tid&1) owns k-slice [part*128, +128) of gate
//     rows {u, 256+u, 512+u}.
// ---------------------------------------------------------------------------
#define LD16(V, P, Q) { \
  uint4 a_ = (P)[(Q)*4+0], b_ = (P)[(Q)*4+1], c_ = (P)[(Q)*4+2], d_ = (P)[(Q)*4+3]; \
  V[0]=a_.x; V[1]=a_.y; V[2]=a_.z; V[3]=a_.w; \
  V[4]=b_.x; V[5]=b_.y; V[6]=b_.z; V[7]=b_.w; \
  V[8]=c_.x; V[9]=c_.y; V[10]=c_.z; V[11]=c_.w; \
  V[12]=d_.x; V[13]=d_.y; V[14]=d_.z; V[15]=d_.w; }

#define D1(H, W, E, acc) acc = __builtin_amdgcn_fdot2((H), bch((W)[E]), (acc), false);
#define BLK(C, WR, WZ, WN, E) { \
  uint4 hv_ = hp[C]; \
  h2t h0_ = bch(hv_.x), h1_ = bch(hv_.y), h2_ = bch(hv_.z), h3_ = bch(hv_.w); \
  D1(h0_, WR, (E)+0, pr0) D1(h0_, WZ, (E)+0, pz0) D1(h0_, WN, (E)+0, pn0) \
  D1(h1_, WR, (E)+1, pr1) D1(h1_, WZ, (E)+1, pz1) D1(h1_, WN, (E)+1, pn1) \
  D1(h2_, WR, (E)+2, pr0) D1(h2_, WZ, (E)+2, pz0) D1(h2_, WN, (E)+2, pn0) \
  D1(h3_, WR, (E)+3, pr1) D1(h3_, WZ, (E)+3, pz1) D1(h3_, WN, (E)+3, pn1) }

__global__ __launch_bounds__(512) void k_gru_batch(
    const u16* __restrict__ gih, const unsigned* __restrict__ wpk,
    const float* __restrict__ bhh, u16* __restrict__ ob,
    float* __restrict__ hatt, int b0)
{
  __shared__ h2t s_h2[2][128];
  const int tid = threadIdx.x;
  const int u = tid >> 1, part = tid & 1;
  const int bl = blockIdx.x;
  const int b = b0 + bl;

  const uint4* wr4 = (const uint4*)(wpk + ((size_t)(      u) * 128) + part * 64);
  const uint4* wz4 = (const uint4*)(wpk + ((size_t)(256 + u) * 128) + part * 64);
  const uint4* wn4 = (const uint4*)(wpk + ((size_t)(512 + u) * 128) + part * 64);

  u32x16 wr0, wr1, wr2, wr3, wz0, wz1, wz2, wz3, wn0, wn1, wn2, wn3;
  LD16(wr0, wr4, 0) LD16(wr1, wr4, 1) LD16(wr2, wr4, 2) LD16(wr3, wr4, 3)
  LD16(wz0, wz4, 0) LD16(wz1, wz4, 1) LD16(wz2, wz4, 2) LD16(wz3, wz4, 3)
  LD16(wn0, wn4, 0) LD16(wn1, wn4, 1) LD16(wn2, wn4, 2) LD16(wn3, wn4, 3)

  float bh_r = 0.f, bh_z = 0.f, bh_n = 0.f;
  if (part == 0) { bh_r = bhh[u]; bh_z = bhh[256 + u]; bh_n = bhh[512 + u]; }
  if (tid < 128) s_h2[0][tid] = pk(0.f, 0.f);
  __syncthreads();

  float hprev = 0.f;
  int cur = 0;
  for (int t = 0; t < 1000; ++t) {
    float gi_r = 0.f, gi_z = 0.f, gi_n = 0.f;
    if (part == 0) {
      const u16* gr_ = gih + ((size_t)bl * 1000 + t) * 768;
      gi_r = bf2f(gr_[u]); gi_z = bf2f(gr_[256 + u]); gi_n = bf2f(gr_[512 + u]);
    }
    const uint4* hp = (const uint4*)&s_h2[cur][part * 64];
    float pr0 = 0.f, pr1 = 0.f, pz0 = 0.f, pz1 = 0.f, pn0 = 0.f, pn1 = 0.f;
    BLK( 0, wr0, wz0, wn0,  0) BLK( 1, wr0, wz0, wn0,  4)
    BLK( 2, wr0, wz0, wn0,  8) BLK( 3, wr0, wz0, wn0, 12)
    BLK( 4, wr1, wz1, wn1,  0) BLK( 5, wr1, wz1, wn1,  4)
    BLK( 6, wr1, wz1, wn1,  8) BLK( 7, wr1, wz1, wn1, 12)
    BLK( 8, wr2, wz2, wn2,  0) BLK( 9, wr2, wz2, wn2,  4)
    BLK(10, wr2, wz2, wn2,  8) BLK(11, wr2, wz2, wn2, 12)
    BLK(12, wr3, wz3, wn3,  0) BLK(13, wr3, wz3, wn3,  4)
    BLK(14, wr3, wz3, wn3,  8) BLK(15, wr3, wz3, wn3, 12)
    float pr = pr0 + pr1, pz = pz0 + pz1, pn = pn0 + pn1;
    pr += __shfl_xor(pr, 1);
    pz += __shfl_xor(pz, 1);
    pn += __shfl_xor(pn, 1);
    float hnew = 0.f;
    if (part == 0) {
      float r = sigf(gi_r + pr + bh_r);
      float z = sigf(gi_z + pz + bh_z);
      float n = tanhfast(gi_n + r * (pn + bh_n));
      hnew = (1.f - z) * n + z * hprev;
      hprev = hnew;
      ob[((size_t)b * 1000 + t) * 256 + u] = f2bf(hnew);
      if (t == 999) hatt[b * 256 + u] = hnew;
    }
    float hother = __shfl_xor(hnew, 2);
    if ((tid & 3) == 0) s_h2[cur ^ 1][tid >> 2] = pk(hnew, hother);
    __syncthreads();
    cur ^= 1;
  }
}

// ---------------------------------------------------------------------------
// K4: snr GRU (unchanged)
// ---------------------------------------------------------------------------
__global__ __launch_bounds__(256) void k_gru_snr(
    const u16* __restrict__ ob, const float* __restrict__ wih,
    const float* __restrict__ whh, const float* __restrict__ bih,
    const float* __restrict__ bhh, const float* __restrict__ fcw,
    const float* __restrict__ fcb,
    float* __restrict__ lsnr_out, float* __restrict__ hsnr_out)
{
  __shared__ float s_wi[48][260];
  __shared__ float s_wh[48][20];
  __shared__ float s_o[16][260];
  __shared__ float s_h[16][20];
  const int tid = threadIdx.x, wg = blockIdx.x;
  const int n0 = wg * 16;
  for (int i = tid; i < 48 * 256; i += 256) s_wi[i >> 8][i & 255] = wih[i];
  for (int i = tid; i < 768; i += 256) s_wh[i >> 4][i & 15] = whh[i];
  const int n = tid >> 4, u = tid & 15;
  const bool valid = (n0 + n) < 1000;
  s_h[n][u] = 0.f;
  float hcur = 0.f;
  const float bi_r = bih[u], bi_z = bih[16 + u], bi_n = bih[32 + u];
  const float bh_r = bhh[u], bh_z = bhh[16 + u], bh_n = bhh[32 + u];
  const float fw = fcw[u], fb = fcb[0];
  __syncthreads();
  for (int step = 0; step < 32; ++step) {
    for (int i = tid; i < 512; i += 256) {
      int nn = i >> 5, c8 = (i & 31) * 8;
      int row = n0 + nn;
      if (row < 1000) {
        u16x8 v = *(const u16x8*)(ob + ((size_t)step * 1000 + row) * 256 + c8);
        #pragma unroll
        for (int j = 0; j < 8; ++j) s_o[nn][c8 + j] = bf2f(v[j]);
      } else {
        #pragma unroll
        for (int j = 0; j < 8; ++j) s_o[nn][c8 + j] = 0.f;
      }
    }
    __syncthreads();
    float gr = bi_r, gz = bi_z, gn = bi_n;
    {
      const float4* o4 = (const float4*)&s_o[n][0];
      const float4* wr = (const float4*)&s_wi[u][0];
      const float4* wz = (const float4*)&s_wi[16 + u][0];
      const float4* wn = (const float4*)&s_wi[32 + u][0];
      #pragma unroll 4
      for (int k4 = 0; k4 < 64; ++k4) {
        float4 ov = o4[k4];
        float4 a = wr[k4], c = wz[k4], d = wn[k4];
        gr += ov.x*a.x + ov.y*a.y + ov.z*a.z + ov.w*a.w;
        gz += ov.x*c.x + ov.y*c.y + ov.z*c.z + ov.w*c.w;
        gn += ov.x*d.x + ov.y*d.y + ov.z*d.z + ov.w*d.w;
      }
    }
    float hr = bh_r, hz = bh_z, hn_ = bh_n;
    #pragma unroll
    for (int k = 0; k < 16; ++k) {
      float hv = s_h[n][k];
      hr  += s_wh[u][k] * hv;
      hz  += s_wh[16 + u][k] * hv;
      hn_ += s_wh[32 + u][k] * hv;
    }
    float r = sigf(gr + hr);
    float z = sigf(gz + hz);
    float nn2 = tanhfast(gn + r * hn_);
    float hnew = (1.f - z) * nn2 + z * hcur;
    __syncthreads();
    s_h[n][u] = hnew;
    hcur = hnew;
    float part = hnew * fw;
    #pragma unroll
    for (int m = 8; m >= 1; m >>= 1) part += __shfl_xor(part, m);
    if (u == 0 && valid) lsnr_out[step * 1000 + n0 + n] = sigf(part + fb) * 50.f - 15.f;
    __syncthreads();
  }
  if (valid) hsnr_out[(size_t)(n0 + n) * 16 + u] = hcur;
}

// ---------------------------------------------------------------------------
// K5: final (unchanged)
// ---------------------------------------------------------------------------
__global__ __launch_bounds__(256) void k_final(
    const u16* __restrict__ x1g, const u16* __restrict__ ob,
    const float* __restrict__ lng, const float* __restrict__ lnb,
    const float* __restrict__ c2w, const float* __restrict__ c2b,
    const float* __restrict__ g2, const float* __restrict__ be2,
    float* __restrict__ m_out)
{
  const int bt = blockIdx.x, tid = threadIdx.x;
  __shared__ float s_xe[8][34];
  __shared__ float s_y[32];
  const int c = tid >> 5, f = tid & 31;
  float v = bf2f(x1g[(size_t)bt * 256 + tid]) + bf2f(ob[(size_t)bt * 256 + tid]);
  float s = v, ss = v * v;
  #pragma unroll
  for (int m = 16; m >= 1; m >>= 1) { s += __shfl_xor(s, m); ss += __shfl_xor(ss, m); }
  float mu = s * (1.f/32.f), rs = rsqrtf(ss * (1.f/32.f) - mu * mu + 1e-5f);
  s_xe[c][1 + f] = (v - mu) * rs * lng[f] + lnb[f];
  if (tid < 8) { s_xe[tid][0] = 0.f; s_xe[tid][33] = 0.f; }
  __syncthreads();
  if (tid < 32) {
    float a = c2b[0];
    #pragma unroll
    for (int cc = 0; cc < 8; ++cc) {
      const float* wr = c2w + cc * 3;
      a += wr[0]*s_xe[cc][tid] + wr[1]*s_xe[cc][tid+1] + wr[2]*s_xe[cc][tid+2];
    }
    s_y[tid] = a;
  }
  __syncthreads();
  if (tid < 32) {
    float y = s_y[tid];
    float s2 = y, ss2 = y * y;
    #pragma unroll
    for (int m = 16; m >= 1; m >>= 1) { s2 += __shfl_xor(s2, m); ss2 += __shfl_xor(ss2, m); }
    float mu2 = s2 * (1.f/32.f), rs2 = rsqrtf(ss2 * (1.f/32.f) - mu2 * mu2 + 1e-5f);
    float yn = (y - mu2) * rs2 * g2[tid] + be2[tid];
    m_out[(size_t)bt * 32 + tid] = sigf(yn);
  }
}

// ---------------------------------------------------------------------------
extern "C" void kernel_launch(void* const* d_in, const int* in_sizes, int n_in,
                              void* d_out, int out_size, void* d_ws, size_t ws_size,
                              hipStream_t stream)
{
  const float* input = (const float*)d_in[0];
  const float* w0    = (const float*)d_in[1];
  const float* b0    = (const float*)d_in[2];
  const float* ln0g  = (const float*)d_in[3];
  const float* ln0b  = (const float*)d_in[4];
  const float* w1    = (const float*)d_in[5];
  const float* b1    = (const float*)d_in[6];
  const float* ln1g  = (const float*)d_in[7];
  const float* ln1b  = (const float*)d_in[8];
  const float* qw    = (const float*)d_in[9];
  const float* qb    = (const float*)d_in[10];
  const float* kw    = (const float*)d_in[11];
  const float* kb    = (const float*)d_in[12];
  const float* vw    = (const float*)d_in[13];
  const float* vb    = (const float*)d_in[14];
  const float* gwih  = (const float*)d_in[15];
  const float* gwhh  = (const float*)d_in[16];
  const float* gbih  = (const float*)d_in[17];
  const float* gbhh  = (const float*)d_in[18];
  const float* lng   = (const float*)d_in[19];
  const float* lnb   = (const float*)d_in[20];
  const float* swih  = (const float*)d_in[21];
  const float* swhh  = (const float*)d_in[22];
  const float* sbih  = (const float*)d_in[23];
  const float* sbhh  = (const float*)d_in[24];
  const float* fcw   = (const float*)d_in[25];
  const float* fcb   = (const float*)d_in[26];
  const float* c2w   = (const float*)d_in[27];
  const float* c2b   = (const float*)d_in[28];
  const float* ln2g  = (const float*)d_in[29];
  const float* ln2b  = (const float*)d_in[30];
  (void)in_sizes; (void)n_in; (void)out_size;

  char* ws = (char*)d_ws;
  size_t off = 0;
  auto take = [&](size_t bytes) -> void* {
    void* p = ws + off;
    off += (bytes + 255) & ~(size_t)255;
    return p;
  };
  u16* x1g      = (u16*)take((size_t)32000 * 256 * 2);
  u16* ob       = (u16*)take((size_t)32000 * 256 * 2);
  u16* gwb      = (u16*)take((size_t)768 * 2048 * 2);     // bf16 gruo_wih
  unsigned* wpk = (unsigned*)take((size_t)768 * 128 * 4); // packed f16 whh

  // Adaptive sizing: GB (batch group) first, then the largest CH that fits.
  const size_t fixedoff = off;
  int GB = 32;
  while (GB > 1) {
    size_t need = fixedoff + ((size_t)GB * 1000 * 768 * 2 + 256)
                           + ((size_t)4096 * 2048 * 2 + 256);
    if (need <= ws_size) break;
    GB >>= 1;
  }
  u16* gih = (u16*)take((size_t)GB * 1000 * 768 * 2);
  int CH = GB * 1000;                       // want a single chunk
  while (CH > 4096) {
    if (off + ((size_t)CH * 2048 * 2 + 256) <= ws_size) break;
    CH >>= 1;
  }
  if (CH > GB * 1000) CH = GB * 1000;
  CH = (CH + 63) & ~63;
  u16* gi = (u16*)take((size_t)CH * 2048 * 2);

  float* out      = (float*)d_out;
  float* m_out    = out;                 // [32,1,1000,32] = 1,024,000
  float* lsnr_out = out + 1024000;       // [32,1000,1]    =    32,000
  float* hatt_out = out + 1056000;       // [1,32,256]     =     8,192
  float* hsnr_out = out + 1064192;       // [1,1000,16]    =    16,000

  k_wcvt<<<768, 256, 0, stream>>>(gwih, gwb);
  k_wcvt2<<<384, 256, 0, stream>>>(gwhh, wpk);

  const int NG = 32 / GB;
  for (int g = 0; g < NG; ++g) {
    const int row0 = g * GB * 1000, rows = GB * 1000;
    for (int c0 = 0; c0 < rows; c0 += CH) {
      const int Mc = (rows - c0 < CH) ? (rows - c0) : CH;
      k_frontend<<<Mc, 256, 0, stream>>>(input, w0, b0, ln0g, ln0b, w1, b1,
                                         ln1g, ln1b, qw, qb, kw, kb, vw, vb,
                                         row0 + c0, x1g, gi);
      dim3 gg((Mc + 127) / 128, 3);
      k_gemm_mfma<<<gg, 512, 0, stream>>>(gi, gwb, gbih, gih + (size_t)c0 * 768, Mc);
    }
    k_gru_batch<<<GB, 512, 0, stream>>>(gih, wpk, gbhh, ob, hatt_out, g * GB);
  }
  k_gru_snr<<<64, 256, 0, stream>>>(ob, swih, swhh, sbih, sbhh, fcw, fcb,
                                    lsnr_out, hsnr_out);
  k_final<<<32000, 256, 0, stream>>>(x1g, ob, lng, lnb, c2w, c2b, ln2g, ln2b, m_out);
}

// Round 15
// 2185.743 us; speedup vs baseline: 1.2549x; 1.0207x over previous
//
#include <hip/hip_runtime.h>

// ErbStage: conv0+LN+ReLU -> conv1+LN+ReLU -> spectral attention -> GRU(T=1000)
//           -> GRU(B=32 scan) + lsnr -> LN/conv2/LN/sigmoid mask.
//
// R15: k_gru_batch LDS pad: s_h2 rows 128->136 h2t, part stride 68 (byte 272,
//      bank 4) so part0/part1 ds_read_b128 halves hit disjoint banks
//      (kills the constant 1.64e7 SQ_LDS_BANK_CONFLICT). hatt store hoisted
//      out of the t-loop. wcvt+wcvt2 fused into one launch.

typedef unsigned short u16;
typedef u16 u16x8 __attribute__((ext_vector_type(8)));
typedef short s16x8 __attribute__((ext_vector_type(8)));
typedef float f32x4 __attribute__((ext_vector_type(4)));
typedef _Float16 h2t __attribute__((ext_vector_type(2)));
typedef unsigned int u32x16 __attribute__((ext_vector_type(16)));

__device__ __forceinline__ float sigf(float x) { return 1.f / (1.f + __expf(-x)); }
__device__ __forceinline__ float tanhfast(float x) { return 2.f / (1.f + __expf(-2.f * x)) - 1.f; }
__device__ __forceinline__ float bf2f(u16 s) { union { unsigned u; float f; } x; x.u = ((unsigned)s) << 16; return x.f; }
__device__ __forceinline__ u16 f2bf(float f) {
  union { float f; unsigned u; } x; x.f = f;
  unsigned r = x.u + 0x7fffu + ((x.u >> 16) & 1u);
  return (u16)(r >> 16);
}
__device__ __forceinline__ h2t pk(float a, float b) {
  auto v = __builtin_amdgcn_cvt_pkrtz(a, b);
  union { decltype(v) i; h2t o; } u; u.i = v; return u.o;
}
__device__ __forceinline__ h2t bch(unsigned x) { return __builtin_bit_cast(h2t, x); }

// ---------------------------------------------------------------------------
// K0: one-time weight converts, fused. Blocks [0,768): gruo_wih f32->bf16.
//     Blocks [768,1152): whh f32->packed f16 pairs.
// ---------------------------------------------------------------------------
__global__ __launch_bounds__(256) void k_wcvt_all(
    const float* __restrict__ W, u16* __restrict__ Wb,
    const float* __restrict__ Wh, unsigned* __restrict__ Wp)
{
  if (blockIdx.x < 768) {
    const size_t i = ((size_t)blockIdx.x * 256 + threadIdx.x) * 8;
    float4 a = *(const float4*)(W + i);
    float4 b = *(const float4*)(W + i + 4);
    u16x8 o;
    o[0] = f2bf(a.x); o[1] = f2bf(a.y); o[2] = f2bf(a.z); o[3] = f2bf(a.w);
    o[4] = f2bf(b.x); o[5] = f2bf(b.y); o[6] = f2bf(b.z); o[7] = f2bf(b.w);
    *(u16x8*)(Wb + i) = o;
  } else {
    const size_t i = (size_t)(blockIdx.x - 768) * 256 + threadIdx.x; // 98304 u32
    float2 a = *(const float2*)(Wh + i * 2);
    Wp[i] = __builtin_bit_cast(unsigned, pk(a.x, a.y));
  }
}

// ---------------------------------------------------------------------------
// K1: fused frontend per (b,t)
// ---------------------------------------------------------------------------
__global__ __launch_bounds__(256) void k_frontend(
    const float* __restrict__ in,
    const float* __restrict__ w0c, const float* __restrict__ b0c,
    const float* __restrict__ g0, const float* __restrict__ be0,
    const float* __restrict__ w1c, const float* __restrict__ b1c,
    const float* __restrict__ g1, const float* __restrict__ be1,
    const float* __restrict__ qw, const float* __restrict__ qb,
    const float* __restrict__ kw, const float* __restrict__ kb,
    const float* __restrict__ vw, const float* __restrict__ vb,
    int bt0, u16* __restrict__ x1g, u16* __restrict__ gi)
{
  const int bt = bt0 + blockIdx.x, tid = threadIdx.x;
  __shared__ float s_in[34];
  __shared__ float s_x0[16][34];
  __shared__ float s_x1[8][34];
  __shared__ float s_q[64][36];
  __shared__ float s_k[64][36];
  __shared__ float s_v[32][68];
  __shared__ float s_sc[32][36];
  __shared__ float s_red[8];
  __shared__ float s_mu[16], s_rs[16];

  if (tid < 32) s_in[1 + tid] = in[(size_t)bt * 32 + tid];
  if (tid == 0) { s_in[0] = 0.f; s_in[33] = 0.f; }
  __syncthreads();

  // conv0 (1->16)
  #pragma unroll
  for (int i = 0; i < 2; ++i) {
    int o = tid + i * 256, c = o >> 5, f = o & 31;
    float a = b0c[c] + w0c[c*3]*s_in[f] + w0c[c*3+1]*s_in[f+1] + w0c[c*3+2]*s_in[f+2];
    s_x0[c][1 + f] = a;
  }
  __syncthreads();
  {
    int c = tid >> 4, i = tid & 15;
    float a = s_x0[c][1 + i], b = s_x0[c][17 + i];
    float s = a + b, ss = a * a + b * b;
    #pragma unroll
    for (int m = 8; m >= 1; m >>= 1) { s += __shfl_xor(s, m); ss += __shfl_xor(ss, m); }
    if (i == 0) { float mu = s * (1.f/32.f); s_mu[c] = mu; s_rs[c] = rsqrtf(ss * (1.f/32.f) - mu*mu + 1e-5f); }
  }
  __syncthreads();
  #pragma unroll
  for (int i = 0; i < 2; ++i) {
    int o = tid + i * 256, c = o >> 5, f = o & 31;
    float v = (s_x0[c][1 + f] - s_mu[c]) * s_rs[c] * g0[f] + be0[f];
    s_x0[c][1 + f] = fmaxf(v, 0.f);
  }
  if (tid < 16) { s_x0[tid][0] = 0.f; s_x0[tid][33] = 0.f; }
  __syncthreads();

  // conv1 (16->8) + ln1 + relu
  {
    int c = tid >> 5, f = tid & 31;
    float a = b1c[c];
    #pragma unroll
    for (int cc = 0; cc < 16; ++cc) {
      const float* wr = w1c + (c * 16 + cc) * 3;
      a += wr[0]*s_x0[cc][f] + wr[1]*s_x0[cc][f+1] + wr[2]*s_x0[cc][f+2];
    }
    float s = a, ss = a * a;
    #pragma unroll
    for (int m = 16; m >= 1; m >>= 1) { s += __shfl_xor(s, m); ss += __shfl_xor(ss, m); }
    float mu = s * (1.f/32.f), rs = rsqrtf(ss * (1.f/32.f) - mu*mu + 1e-5f);
    float v = fmaxf((a - mu) * rs * g1[f] + be1[f], 0.f);
    s_x1[c][1 + f] = v;
    x1g[(size_t)bt * 256 + tid] = f2bf(v);
  }
  if (tid < 8) { s_x1[tid][0] = 0.f; s_x1[tid][33] = 0.f; }
  __syncthreads();

  // q/k/v convs (8->64 each)
  {
    int h = tid >> 2, fg = tid & 3;
    float aq[8], ak[8], av[8];
    float qbv = qb[h], kbv = kb[h], vbv = vb[h];
    #pragma unroll
    for (int i = 0; i < 8; ++i) { aq[i] = qbv; ak[i] = kbv; av[i] = vbv; }
    #pragma unroll
    for (int c = 0; c < 8; ++c) {
      const float* qr = qw + (h * 8 + c) * 3;
      const float* kr = kw + (h * 8 + c) * 3;
      const float* vr = vw + (h * 8 + c) * 3;
      float q0 = qr[0], q1 = qr[1], q2 = qr[2];
      float k0 = kr[0], k1 = kr[1], k2 = kr[2];
      float v0 = vr[0], v1 = vr[1], v2 = vr[2];
      #pragma unroll
      for (int i = 0; i < 8; ++i) {
        int f = fg + i * 4;
        float xa = s_x1[c][f], xb = s_x1[c][f+1], xc = s_x1[c][f+2];
        aq[i] += q0*xa + q1*xb + q2*xc;
        ak[i] += k0*xa + k1*xb + k2*xc;
        av[i] += v0*xa + v1*xb + v2*xc;
      }
    }
    #pragma unroll
    for (int i = 0; i < 8; ++i) {
      int f = fg + i * 4;
      s_q[h][f] = aq[i];
      s_k[h][f] = ak[i];
      s_v[f][h] = av[i];
    }
  }
  __syncthreads();

  // scores
  const int sf = tid >> 3, sgq = tid & 7;
  float sc0 = 0.f, sc1 = 0.f, sc2 = 0.f, sc3 = 0.f;
  #pragma unroll 8
  for (int h = 0; h < 64; ++h) {
    float q = s_q[h][sf];
    float4 k4 = *(const float4*)&s_k[h][sgq * 4];
    sc0 += q * k4.x; sc1 += q * k4.y; sc2 += q * k4.z; sc3 += q * k4.w;
  }
  sc0 *= 0.125f; sc1 *= 0.125f; sc2 *= 0.125f; sc3 *= 0.125f;
  float mx = fmaxf(fmaxf(sc0, sc1), fmaxf(sc2, sc3));
  #pragma unroll
  for (int m = 32; m >= 1; m >>= 1) mx = fmaxf(mx, __shfl_xor(mx, m));
  if ((tid & 63) == 0) s_red[tid >> 6] = mx;
  __syncthreads();
  mx = fmaxf(fmaxf(s_red[0], s_red[1]), fmaxf(s_red[2], s_red[3]));
  sc0 = __expf(sc0 - mx); sc1 = __expf(sc1 - mx);
  sc2 = __expf(sc2 - mx); sc3 = __expf(sc3 - mx);
  float sm = sc0 + sc1 + sc2 + sc3;
  #pragma unroll
  for (int m = 32; m >= 1; m >>= 1) sm += __shfl_xor(sm, m);
  __syncthreads();
  if ((tid & 63) == 0) s_red[4 + (tid >> 6)] = sm;
  __syncthreads();
  float inv = 1.f / (s_red[4] + s_red[5] + s_red[6] + s_red[7]);
  {
    float4 o4; o4.x = sc0 * inv; o4.y = sc1 * inv; o4.z = sc2 * inv; o4.w = sc3 * inv;
    *(float4*)&s_sc[sf][sgq * 4] = o4;
  }
  __syncthreads();

  // att
  {
    const int f = tid >> 3, hq = tid & 7;
    float a0=0,a1=0,a2=0,a3=0,a4=0,a5=0,a6=0,a7=0;
    #pragma unroll 8
    for (int g = 0; g < 32; ++g) {
      float w = s_sc[f][g];
      float4 v0 = *(const float4*)&s_v[g][hq * 8];
      float4 v1 = *(const float4*)&s_v[g][hq * 8 + 4];
      a0 += w * v0.x; a1 += w * v0.y; a2 += w * v0.z; a3 += w * v0.w;
      a4 += w * v1.x; a5 += w * v1.y; a6 += w * v1.z; a7 += w * v1.w;
    }
    u16x8 ov;
    ov[0] = f2bf(a0); ov[1] = f2bf(a1); ov[2] = f2bf(a2); ov[3] = f2bf(a3);
    ov[4] = f2bf(a4); ov[5] = f2bf(a5); ov[6] = f2bf(a6); ov[7] = f2bf(a7);
    *(u16x8*)(gi + (size_t)blockIdx.x * 2048 + f * 64 + hq * 8) = ov;
  }
}

// ---------------------------------------------------------------------------
// K2: MFMA GEMM: C[M,768](bf16) = A[M,2048](bf16) @ Wb[768,2048]^T + bias
// ---------------------------------------------------------------------------
__global__ __launch_bounds__(512, 2) void k_gemm_mfma(
    const u16* __restrict__ A, const u16* __restrict__ Wb,
    const float* __restrict__ bias, u16* __restrict__ C, int M)
{
  __shared__ u16 lA[128][40];
  __shared__ u16 lB[256][40];
  const int tid = threadIdx.x;
  const int m0 = blockIdx.x * 128, n0 = blockIdx.y * 256;
  const int w = tid >> 6, l = tid & 63;
  const int wr = w >> 2, wc = w & 3;
  const int fr = l & 15, fg = l >> 4;
  f32x4 acc[4][4] = {};
  const int ar = tid >> 2, akc = tid & 3;
  const int br = tid >> 1, bkc = tid & 1;
  for (int k0 = 0; k0 < 2048; k0 += 32) {
    int am = m0 + ar;
    u16x8 av = (u16x8)(u16)0;
    if (am < M) av = *(const u16x8*)(A + (size_t)am * 2048 + k0 + akc * 8);
    *(u16x8*)&lA[ar][akc * 8] = av;
    const u16* bp = Wb + (size_t)(n0 + br) * 2048 + k0 + bkc * 16;
    u16x8 bv0 = *(const u16x8*)bp;
    u16x8 bv1 = *(const u16x8*)(bp + 8);
    *(u16x8*)&lB[br][bkc * 16] = bv0;
    *(u16x8*)&lB[br][bkc * 16 + 8] = bv1;
    __syncthreads();
    #pragma unroll
    for (int mi = 0; mi < 4; ++mi) {
      s16x8 afr = *(const s16x8*)&lA[wr * 64 + mi * 16 + fr][fg * 8];
      #pragma unroll
      for (int ni = 0; ni < 4; ++ni) {
        s16x8 bfr = *(const s16x8*)&lB[wc * 64 + ni * 16 + fr][fg * 8];
        acc[mi][ni] = __builtin_amdgcn_mfma_f32_16x16x32_bf16(afr, bfr, acc[mi][ni], 0, 0, 0);
      }
    }
    __syncthreads();
  }
  #pragma unroll
  for (int mi = 0; mi < 4; ++mi) {
    #pragma unroll
    for (int ni = 0; ni < 4; ++ni) {
      int col = n0 + wc * 64 + ni * 16 + (l & 15);
      float bv = bias[col];
      #pragma unroll
      for (int i = 0; i < 4; ++i) {
        int row = m0 + wr * 64 + mi * 16 + (l >> 4) * 4 + i;
        if (row < M) C[(size_t)row * 768 + col] = f2bf(acc[mi][ni][i] + bv);
      }
    }
  }
}

// ---------------------------------------------------------------------------
// K3: main GRU over T=1000 (R12 structure, LDS bank-pad).
//     512 thr/block, one block per batch element. Packed-f16 weights as SSA
//     u32x16 vectors assembled OUTSIDE the t-loop (compiler sinks the loads
//     into the loop -> pipelined stream). Thread (u=tid>>1, part=tid&1) owns
//     k-slice [part*128, +128) of gate rows {u, 256+u, 512+u}.
//     s_h2 rows padded to 136 h2t: part1 base at h2t 68 (byte 272 -> bank 4)
//     so part0/part1 ds_read_b128 halves hit disjoint bank quads.
// ---------------------------------------------------------------------------
#define LD16(V, P, Q) { \
  uint4 a_ = (P)[(Q)*4+0], b_ = (P)[(Q)*4+1], c_ = (P)[(Q)*4+2], d_ = (P)[(Q)*4+3]; \
  V[0]=a_.x; V[1]=a_.y; V[2]=a_.z; V[3]=a_.w; \
  V[4]=b_.x; V[5]=b_.y; V[6]=b_.z; V[7]=b_.w; \
  V[8]=c_.x; V[9]=c_.y; V[10]=c_.z; V[11]=c_.w; \
  V[12]=d_.x; V[13]=d_.y; V[14]=d_.z; V[15]=d_.w; }

#define D1(H, W, E, acc) acc = __builtin_amdgcn_fdot2((H), bch((W)[E]), (acc), false);
#define BLK(C, WR, WZ, WN, E) { \
  uint4 hv_ = hp[C]; \
  h2t h0_ = bch(hv_.x), h1_ = bch(hv_.y), h2_ = bch(hv_.z), h3_ = bch(hv_.w); \
  D1(h0_, WR, (E)+0, pr0) D1(h0_, WZ, (E)+0, pz0) D1(h0_, WN, (E)+0, pn0) \
  D1(h1_, WR, (E)+1, pr1) D1(h1_, WZ, (E)+1, pz1) D1(h1_, WN, (E)+1, pn1) \
  D1(h2_, WR, (E)+2, pr0) D1(h2_, WZ, (E)+2, pz0) D1(h2_, WN, (E)+2, pn0) \
  D1(h3_, WR, (E)+3, pr1) D1(h3_, WZ, (E)+3, pz1) D1(h3_, WN, (E)+3, pn1) }

__global__ __launch_bounds__(512) void k_gru_batch(
    const u16* __restrict__ gih, const unsigned* __restrict__ wpk,
    const float* __restrict__ bhh, u16* __restrict__ ob,
    float* __restrict__ hatt, int b0)
{
  __shared__ h2t s_h2[2][136];   // part0 at [0,64), part1 at [68,132)
  const int tid = threadIdx.x;
  const int u = tid >> 1, part = tid & 1;
  const int bl = blockIdx.x;
  const int b = b0 + bl;

  const uint4* wr4 = (const uint4*)(wpk + ((size_t)(      u) * 128) + part * 64);
  const uint4* wz4 = (const uint4*)(wpk + ((size_t)(256 + u) * 128) + part * 64);
  const uint4* wn4 = (const uint4*)(wpk + ((size_t)(512 + u) * 128) + part * 64);

  u32x16 wr0, wr1, wr2, wr3, wz0, wz1, wz2, wz3, wn0, wn1, wn2, wn3;
  LD16(wr0, wr4, 0) LD16(wr1, wr4, 1) LD16(wr2, wr4, 2) LD16(wr3, wr4, 3)
  LD16(wz0, wz4, 0) LD16(wz1, wz4, 1) LD16(wz2, wz4, 2) LD16(wz3, wz4, 3)
  LD16(wn0, wn4, 0) LD16(wn1, wn4, 1) LD16(wn2, wn4, 2) LD16(wn3, wn4, 3)

  float bh_r = 0.f, bh_z = 0.f, bh_n = 0.f;
  if (part == 0) { bh_r = bhh[u]; bh_z = bhh[256 + u]; bh_n = bhh[512 + u]; }
  if (tid < 128) s_h2[0][tid + (tid >> 6) * 4] = pk(0.f, 0.f);
  __syncthreads();

  float hprev = 0.f;
  int cur = 0;
  for (int t = 0; t < 1000; ++t) {
    float gi_r = 0.f, gi_z = 0.f, gi_n = 0.f;
    if (part == 0) {
      const u16* gr_ = gih + ((size_t)bl * 1000 + t) * 768;
      gi_r = bf2f(gr_[u]); gi_z = bf2f(gr_[256 + u]); gi_n = bf2f(gr_[512 + u]);
    }
    const uint4* hp = (const uint4*)&s_h2[cur][part * 68];
    float pr0 = 0.f, pr1 = 0.f, pz0 = 0.f, pz1 = 0.f, pn0 = 0.f, pn1 = 0.f;
    BLK( 0, wr0, wz0, wn0,  0) BLK( 1, wr0, wz0, wn0,  4)
    BLK( 2, wr0, wz0, wn0,  8) BLK( 3, wr0, wz0, wn0, 12)
    BLK( 4, wr1, wz1, wn1,  0) BLK( 5, wr1, wz1, wn1,  4)
    BLK( 6, wr1, wz1, wn1,  8) BLK( 7, wr1, wz1, wn1, 12)
    BLK( 8, wr2, wz2, wn2,  0) BLK( 9, wr2, wz2, wn2,  4)
    BLK(10, wr2, wz2, wn2,  8) BLK(11, wr2, wz2, wn2, 12)
    BLK(12, wr3, wz3, wn3,  0) BLK(13, wr3, wz3, wn3,  4)
    BLK(14, wr3, wz3, wn3,  8) BLK(15, wr3, wz3, wn3, 12)
    float pr = pr0 + pr1, pz = pz0 + pz1, pn = pn0 + pn1;
    pr += __shfl_xor(pr, 1);
    pz += __shfl_xor(pz, 1);
    pn += __shfl_xor(pn, 1);
    float hnew = 0.f;
    if (part == 0) {
      float r = sigf(gi_r + pr + bh_r);
      float z = sigf(gi_z + pz + bh_z);
      float n = tanhfast(gi_n + r * (pn + bh_n));
      hnew = (1.f - z) * n + z * hprev;
      hprev = hnew;
      ob[((size_t)b * 1000 + t) * 256 + u] = f2bf(hnew);
    }
    float hother = __shfl_xor(hnew, 2);
    if ((tid & 3) == 0) {
      int j = tid >> 2;                      // 0..127
      s_h2[cur ^ 1][j + (j >> 6) * 4] = pk(hnew, hother);
    }
    __syncthreads();
    cur ^= 1;
  }
  if (part == 0) hatt[b * 256 + u] = hprev;
}

// ---------------------------------------------------------------------------
// K4: snr GRU (unchanged)
// ---------------------------------------------------------------------------
__global__ __launch_bounds__(256) void k_gru_snr(
    const u16* __restrict__ ob, const float* __restrict__ wih,
    const float* __restrict__ whh, const float* __restrict__ bih,
    const float* __restrict__ bhh, const float* __restrict__ fcw,
    const float* __restrict__ fcb,
    float* __restrict__ lsnr_out, float* __restrict__ hsnr_out)
{
  __shared__ float s_wi[48][260];
  __shared__ float s_wh[48][20];
  __shared__ float s_o[16][260];
  __shared__ float s_h[16][20];
  const int tid = threadIdx.x, wg = blockIdx.x;
  const int n0 = wg * 16;
  for (int i = tid; i < 48 * 256; i += 256) s_wi[i >> 8][i & 255] = wih[i];
  for (int i = tid; i < 768; i += 256) s_wh[i >> 4][i & 15] = whh[i];
  const int n = tid >> 4, u = tid & 15;
  const bool valid = (n0 + n) < 1000;
  s_h[n][u] = 0.f;
  float hcur = 0.f;
  const float bi_r = bih[u], bi_z = bih[16 + u], bi_n = bih[32 + u];
  const float bh_r = bhh[u], bh_z = bhh[16 + u], bh_n = bhh[32 + u];
  const float fw = fcw[u], fb = fcb[0];
  __syncthreads();
  for (int step = 0; step < 32; ++step) {
    for (int i = tid; i < 512; i += 256) {
      int nn = i >> 5, c8 = (i & 31) * 8;
      int row = n0 + nn;
      if (row < 1000) {
        u16x8 v = *(const u16x8*)(ob + ((size_t)step * 1000 + row) * 256 + c8);
        #pragma unroll
        for (int j = 0; j < 8; ++j) s_o[nn][c8 + j] = bf2f(v[j]);
      } else {
        #pragma unroll
        for (int j = 0; j < 8; ++j) s_o[nn][c8 + j] = 0.f;
      }
    }
    __syncthreads();
    float gr = bi_r, gz = bi_z, gn = bi_n;
    {
      const float4* o4 = (const float4*)&s_o[n][0];
      const float4* wr = (const float4*)&s_wi[u][0];
      const float4* wz = (const float4*)&s_wi[16 + u][0];
      const float4* wn = (const float4*)&s_wi[32 + u][0];
      #pragma unroll 4
      for (int k4 = 0; k4 < 64; ++k4) {
        float4 ov = o4[k4];
        float4 a = wr[k4], c = wz[k4], d = wn[k4];
        gr += ov.x*a.x + ov.y*a.y + ov.z*a.z + ov.w*a.w;
        gz += ov.x*c.x + ov.y*c.y + ov.z*c.z + ov.w*c.w;
        gn += ov.x*d.x + ov.y*d.y + ov.z*d.z + ov.w*d.w;
      }
    }
    float hr = bh_r, hz = bh_z, hn_ = bh_n;
    #pragma unroll
    for (int k = 0; k < 16; ++k) {
      float hv = s_h[n][k];
      hr  += s_wh[u][k] * hv;
      hz  += s_wh[16 + u][k] * hv;
      hn_ += s_wh[32 + u][k] * hv;
    }
    float r = sigf(gr + hr);
    float z = sigf(gz + hz);
    float nn2 = tanhfast(gn + r * hn_);
    float hnew = (1.f - z) * nn2 + z * hcur;
    __syncthreads();
    s_h[n][u] = hnew;
    hcur = hnew;
    float part = hnew * fw;
    #pragma unroll
    for (int m = 8; m >= 1; m >>= 1) part += __shfl_xor(part, m);
    if (u == 0 && valid) lsnr_out[step * 1000 + n0 + n] = sigf(part + fb) * 50.f - 15.f;
    __syncthreads();
  }
  if (valid) hsnr_out[(size_t)(n0 + n) * 16 + u] = hcur;
}

// ---------------------------------------------------------------------------
// K5: final (unchanged)
// ---------------------------------------------------------------------------
__global__ __launch_bounds__(256) void k_final(
    const u16* __restrict__ x1g, const u16* __restrict__ ob,
    const float* __restrict__ lng, const float* __restrict__ lnb,
    const float* __restrict__ c2w, const float* __restrict__ c2b,
    const float* __restrict__ g2, const float* __restrict__ be2,
    float* __restrict__ m_out)
{
  const int bt = blockIdx.x, tid = threadIdx.x;
  __shared__ float s_xe[8][34];
  __shared__ float s_y[32];
  const int c = tid >> 5, f = tid & 31;
  float v = bf2f(x1g[(size_t)bt * 256 + tid]) + bf2f(ob[(size_t)bt * 256 + tid]);
  float s = v, ss = v * v;
  #pragma unroll
  for (int m = 16; m >= 1; m >>= 1) { s += __shfl_xor(s, m); ss += __shfl_xor(ss, m); }
  float mu = s * (1.f/32.f), rs = rsqrtf(ss * (1.f/32.f) - mu * mu + 1e-5f);
  s_xe[c][1 + f] = (v - mu) * rs * lng[f] + lnb[f];
  if (tid < 8) { s_xe[tid][0] = 0.f; s_xe[tid][33] = 0.f; }
  __syncthreads();
  if (tid < 32) {
    float a = c2b[0];
    #pragma unroll
    for (int cc = 0; cc < 8; ++cc) {
      const float* wr = c2w + cc * 3;
      a += wr[0]*s_xe[cc][tid] + wr[1]*s_xe[cc][tid+1] + wr[2]*s_xe[cc][tid+2];
    }
    s_y[tid] = a;
  }
  __syncthreads();
  if (tid < 32) {
    float y = s_y[tid];
    float s2 = y, ss2 = y * y;
    #pragma unroll
    for (int m = 16; m >= 1; m >>= 1) { s2 += __shfl_xor(s2, m); ss2 += __shfl_xor(ss2, m); }
    float mu2 = s2 * (1.f/32.f), rs2 = rsqrtf(ss2 * (1.f/32.f) - mu2 * mu2 + 1e-5f);
    float yn = (y - mu2) * rs2 * g2[tid] + be2[tid];
    m_out[(size_t)bt * 32 + tid] = sigf(yn);
  }
}

// ---------------------------------------------------------------------------
extern "C" void kernel_launch(void* const* d_in, const int* in_sizes, int n_in,
                              void* d_out, int out_size, void* d_ws, size_t ws_size,
                              hipStream_t stream)
{
  const float* input = (const float*)d_in[0];
  const float* w0    = (const float*)d_in[1];
  const float* b0    = (const float*)d_in[2];
  const float* ln0g  = (const float*)d_in[3];
  const float* ln0b  = (const float*)d_in[4];
  const float* w1    = (const float*)d_in[5];
  const float* b1    = (const float*)d_in[6];
  const float* ln1g  = (const float*)d_in[7];
  const float* ln1b  = (const float*)d_in[8];
  const float* qw    = (const float*)d_in[9];
  const float* qb    = (const float*)d_in[10];
  const float* kw    = (const float*)d_in[11];
  const float* kb    = (const float*)d_in[12];
  const float* vw    = (const float*)d_in[13];
  const float* vb    = (const float*)d_in[14];
  const float* gwih  = (const float*)d_in[15];
  const float* gwhh  = (const float*)d_in[16];
  const float* gbih  = (const float*)d_in[17];
  const float* gbhh  = (const float*)d_in[18];
  const float* lng   = (const float*)d_in[19];
  const float* lnb   = (const float*)d_in[20];
  const float* swih  = (const float*)d_in[21];
  const float* swhh  = (const float*)d_in[22];
  const float* sbih  = (const float*)d_in[23];
  const float* sbhh  = (const float*)d_in[24];
  const float* fcw   = (const float*)d_in[25];
  const float* fcb   = (const float*)d_in[26];
  const float* c2w   = (const float*)d_in[27];
  const float* c2b   = (const float*)d_in[28];
  const float* ln2g  = (const float*)d_in[29];
  const float* ln2b  = (const float*)d_in[30];
  (void)in_sizes; (void)n_in; (void)out_size;

  char* ws = (char*)d_ws;
  size_t off = 0;
  auto take = [&](size_t bytes) -> void* {
    void* p = ws + off;
    off += (bytes + 255) & ~(size_t)255;
    return p;
  };
  u16* x1g      = (u16*)take((size_t)32000 * 256 * 2);
  u16* ob       = (u16*)take((size_t)32000 * 256 * 2);
  u16* gwb      = (u16*)take((size_t)768 * 2048 * 2);     // bf16 gruo_wih
  unsigned* wpk = (unsigned*)take((size_t)768 * 128 * 4); // packed f16 whh

  // Adaptive sizing: GB (batch group) first, then the largest CH that fits.
  const size_t fixedoff = off;
  int GB = 32;
  while (GB > 1) {
    size_t need = fixedoff + ((size_t)GB * 1000 * 768 * 2 + 256)
                           + ((size_t)4096 * 2048 * 2 + 256);
    if (need <= ws_size) break;
    GB >>= 1;
  }
  u16* gih = (u16*)take((size_t)GB * 1000 * 768 * 2);
  int CH = GB * 1000;                       // want a single chunk
  while (CH > 4096) {
    if (off + ((size_t)CH * 2048 * 2 + 256) <= ws_size) break;
    CH >>= 1;
  }
  if (CH > GB * 1000) CH = GB * 1000;
  CH = (CH + 63) & ~63;
  u16* gi = (u16*)take((size_t)CH * 2048 * 2);

  float* out      = (float*)d_out;
  float* m_out    = out;                 // [32,1,1000,32] = 1,024,000
  float* lsnr_out = out + 1024000;       // [32,1000,1]    =    32,000
  float* hatt_out = out + 1056000;       // [1,32,256]     =     8,192
  float* hsnr_out = out + 1064192;       // [1,1000,16]    =    16,000

  k_wcvt_all<<<1152, 256, 0, stream>>>(gwih, gwb, gwhh, wpk);

  const int NG = 32 / GB;
  for (int g = 0; g < NG; ++g) {
    const int row0 = g * GB * 1000, rows = GB * 1000;
    for (int c0 = 0; c0 < rows; c0 += CH) {
      const int Mc = (rows - c0 < CH) ? (rows - c0) : CH;
      k_frontend<<<Mc, 256, 0, stream>>>(input, w0, b0, ln0g, ln0b, w1, b1,
                                         ln1g, ln1b, qw, qb, kw, kb, vw, vb,
                                         row0 + c0, x1g, gi);
      dim3 gg((Mc + 127) / 128, 3);
      k_gemm_mfma<<<gg, 512, 0, stream>>>(gi, gwb, gbih, gih + (size_t)c0 * 768, Mc);
    }
    k_gru_batch<<<GB, 512, 0, stream>>>(gih, wpk, gbhh, ob, hatt_out, g * GB);
  }
  k_gru_snr<<<64, 256, 0, stream>>>(ob, swih, swhh, sbih, sbhh, fcw, fcb,
                                    lsnr_out, hsnr_out);
  k_final<<<32000, 256, 0, stream>>>(x1g, ob, lng, lnb, c2w, c2b, ln2g, ln2b, m_out);
}